// Round 5
// baseline (234.947 us; speedup 1.0000x reference)
//
#include <hip/hip_runtime.h>
#include <hip/hip_bf16.h>
#include <stdint.h>

#define N_PTS 16384
#define M_PTS 2048

#define GLOBAL_AS __attribute__((address_space(1)))
#define LDS_AS    __attribute__((address_space(3)))

typedef __bf16 bf16x8 __attribute__((ext_vector_type(8)));
typedef float  f32x4  __attribute__((ext_vector_type(4)));

// ---------------------------------------------------------------------------
// Kernel 1: K[i][j] = exp(-||x_i - z_j||_1) -> bf16.
// Thread t owns j = t*8..t*8+7 (z cached in 32 VGPRs, amortized over 16
// rows); stores are bf16x8 (16 B/lane, 1 KB/wave). Grid 1024 blocks.
// ---------------------------------------------------------------------------
__global__ __launch_bounds__(256) void laplace_k(
    const float* __restrict__ x, const float* __restrict__ z,
    __hip_bfloat16* __restrict__ Kout) {
  const int t  = threadIdx.x;
  const int i0 = blockIdx.x * 16;
  const int j0 = t * 8;
  float4 zv[8];
#pragma unroll
  for (int e = 0; e < 8; ++e)
    zv[e] = reinterpret_cast<const float4*>(z)[j0 + e];
#pragma unroll
  for (int rr = 0; rr < 16; ++rr) {
    const int i = i0 + rr;
    const float4 xv = *reinterpret_cast<const float4*>(x + (size_t)i * 4);
    bf16x8 outv;
#pragma unroll
    for (int e = 0; e < 8; ++e) {
      const float l1 = fabsf(xv.x - zv[e].x) + fabsf(xv.y - zv[e].y) +
                       fabsf(xv.z - zv[e].z) + fabsf(xv.w - zv[e].w);
      outv[e] = (__bf16)__expf(-l1);
    }
    *reinterpret_cast<bf16x8*>(Kout + (size_t)i * M_PTS + j0) = outv;
  }
}

// ---------------------------------------------------------------------------
// Kernel 2: Bt[j][k] = chol_inv[k][j] -> bf16 (tiled transpose).
// ---------------------------------------------------------------------------
__global__ __launch_bounds__(256) void transpose_cast(
    const float* __restrict__ B, __hip_bfloat16* __restrict__ Bt) {
  __shared__ float tile[32][33];
  const int bj = blockIdx.x * 32;
  const int bk = blockIdx.y * 32;
  const int tx = threadIdx.x, ty = threadIdx.y;
#pragma unroll
  for (int yy = ty; yy < 32; yy += 8)
    tile[yy][tx] = B[(size_t)(bk + yy) * M_PTS + bj + tx];
  __syncthreads();
#pragma unroll
  for (int yy = ty; yy < 32; yy += 8)
    Bt[(size_t)(bj + yy) * M_PTS + bk + tx] = __float2bfloat16(tile[tx][yy]);
}

// ---------------------------------------------------------------------------
// Kernel 3: C = K @ U (triangular), 256x256 tile, BK=64, 8 waves (2Mx4N),
// 8-phase schedule (T2 swizzle + T3/T4 counted vmcnt + T5 setprio).
//
// PERSISTENT EXACT BALANCE: grid = 256 (1 block/CU, LDS 128K forces 1
// resident). Block b -> p=b>>6, it=b&63; computes TWO tiles sharing A-rows:
//   tile0: jt = 7-p  (NT = (8-p)*4 K-tiles)
//   tile1: jt = p    (NT = (p+1)*4)
// Every block: exactly 36 tile-steps, 1.18 MB A + 1.18 MB B reads, 512 KB
// C writes -> zero makespan imbalance, A-panel L2 reuse across the pair.
//
// LDS 128 KiB: [buf(2)][A|B][half(2)][128 rows][64 k] bf16.
// Swizzle (T2, rule 21 both-sides): LDS[row][colb] holds global col-byte
//   colb ^ ((row&7)<<4); writer uses linear dest + pre-swizzled global col
//   (scolE); reader XORs the same. Verified: bank conflicts = 0 (round 4).
//
// Per-tile 8-phase ledger (UNCHANGED from round-4 verified version):
//   P1: A0(t+1)->buf1   P2: A1(t+1), B0(t+2)->buf0   P3: B1(t+2)->buf0
//   P4: vmcnt(4) [last frame vmcnt(0)]
//   P5: A0(t+2)->buf0   P6: A1(t+2), B0(t+3)->buf1   P7: B1(t+3)->buf1
//   P8: vmcnt(4)
// Phase body: ds_reads; stages; [vmcnt]; s_barrier; lgkmcnt(0);
//   sched_barrier(0) [rule 18]; setprio(1); 16 MFMA; setprio(0); s_barrier.
// Tile boundary is safe: last PHASE's trailing barrier follows fully
// drained LDS reads; next prologue stages only after it. vmcnt at the next
// prologue also counts epilogue C-stores -> over-waits (correct, minor).
// ---------------------------------------------------------------------------
__global__ __launch_bounds__(512, 2) void gemm_bf16_8ph(
    const __hip_bfloat16* __restrict__ A,   // [N][2048] bf16 (K matrix)
    const __hip_bfloat16* __restrict__ Bt,  // [2048][2048] bf16, Bt[j][k]
    float* __restrict__ Cmat) {             // [N][2048] fp32
  __shared__ alignas(16) char ldsBuf[131072];
  char* ldsC = ldsBuf;

  const int tid  = threadIdx.x;
  const int lane = tid & 63;
  const int wid  = tid >> 6;  // 0..7
  const int wm   = wid >> 2;  // 0..1 -> A half / row block
  const int wn   = wid & 3;   // 0..3 -> 64-col block
  const int q    = lane >> 4;
  const int r    = lane & 15;

  const int bid = blockIdx.x;
  const int p   = bid >> 6;   // 0..3 -> tile pair (7-p, p)
  const int it  = bid & 63;
  const int iBase = it * 256;

  // ---- staging source pointers (pre-swizzled column, rule 21) ----
  const int srow  = tid >> 3;
  const int scolE = ((tid & 7) ^ ((tid >> 3) & 7)) * 8;
  const __hip_bfloat16* aGp0 = A + (size_t)(iBase + srow) * M_PTS + scolE;
  const __hip_bfloat16* aGp1 = aGp0 + (size_t)128 * M_PTS;

  // ---- LDS read bases (swizzled), kk=0 / kk=1 variants ----
  const int colK0 = (q * 16) ^ ((r & 7) << 4);
  const char* aRd0 = ldsC + wm * 16384 + r * 128 + colK0;
  const char* aRd1 = ldsC + wm * 16384 + r * 128 + (colK0 ^ 64);
  const char* bRd0 = ldsC + 32768 + (wn >> 1) * 16384 +
                     ((wn & 1) * 64 + r) * 128 + colK0;
  const char* bRd1 = ldsC + 32768 + (wn >> 1) * 16384 +
                     ((wn & 1) * 64 + r) * 128 + (colK0 ^ 64);

#define STG(GP, LOFF, KT)                                                    \
  do {                                                                       \
    __builtin_amdgcn_global_load_lds(                                        \
        (const GLOBAL_AS void*)((GP) + (size_t)(KT)*64),                     \
        (LDS_AS void*)(ldsC + (LOFF) + tid * 16), 16, 0, 0);                 \
    __builtin_amdgcn_global_load_lds(                                        \
        (const GLOBAL_AS void*)((GP) + (size_t)(KT)*64 + 64 * M_PTS),        \
        (LDS_AS void*)(ldsC + (LOFF) + 8192 + tid * 16), 16, 0, 0);          \
  } while (0)
#define STG_A0(BUF, KT) STG(aGp0, (BUF)*65536, KT)
#define STG_A1(BUF, KT) STG(aGp1, (BUF)*65536 + 16384, KT)
#define STG_B0(BUF, KT) STG(bGp0, (BUF)*65536 + 32768, KT)
#define STG_B1(BUF, KT) STG(bGp1, (BUF)*65536 + 49152, KT)

#define VM4 asm volatile("s_waitcnt vmcnt(4)" ::: "memory")
#define VM0 asm volatile("s_waitcnt vmcnt(0)" ::: "memory")
#define VMNONE (void)0

#define PHASE(Q2, BOFF, READB, VMW, ...)                                     \
  {                                                                          \
    if (READB) {                                                             \
      _Pragma("unroll") for (int nn = 0; nn < 4; ++nn) {                     \
        bF[nn][0] = *(const bf16x8*)(bRd0 + (BOFF) + nn * 2048);             \
        bF[nn][1] = *(const bf16x8*)(bRd1 + (BOFF) + nn * 2048);             \
      }                                                                      \
    }                                                                        \
    bf16x8 aF0k0 = *(const bf16x8*)(aRd0 + (BOFF) + (Q2 * 2) * 2048);        \
    bf16x8 aF0k1 = *(const bf16x8*)(aRd1 + (BOFF) + (Q2 * 2) * 2048);        \
    bf16x8 aF1k0 = *(const bf16x8*)(aRd0 + (BOFF) + (Q2 * 2 + 1) * 2048);    \
    bf16x8 aF1k1 = *(const bf16x8*)(aRd1 + (BOFF) + (Q2 * 2 + 1) * 2048);    \
    __VA_ARGS__;                                                             \
    VMW;                                                                     \
    __builtin_amdgcn_s_barrier();                                            \
    asm volatile("s_waitcnt lgkmcnt(0)" ::: "memory");                       \
    __builtin_amdgcn_sched_barrier(0);                                       \
    __builtin_amdgcn_s_setprio(1);                                           \
    _Pragma("unroll") for (int nn = 0; nn < 4; ++nn) {                       \
      acc[Q2 * 2][nn] = __builtin_amdgcn_mfma_f32_16x16x32_bf16(             \
          aF0k0, bF[nn][0], acc[Q2 * 2][nn], 0, 0, 0);                       \
      acc[Q2 * 2][nn] = __builtin_amdgcn_mfma_f32_16x16x32_bf16(             \
          aF0k1, bF[nn][1], acc[Q2 * 2][nn], 0, 0, 0);                       \
      acc[Q2 * 2 + 1][nn] = __builtin_amdgcn_mfma_f32_16x16x32_bf16(         \
          aF1k0, bF[nn][0], acc[Q2 * 2 + 1][nn], 0, 0, 0);                   \
      acc[Q2 * 2 + 1][nn] = __builtin_amdgcn_mfma_f32_16x16x32_bf16(         \
          aF1k1, bF[nn][1], acc[Q2 * 2 + 1][nn], 0, 0, 0);                   \
    }                                                                        \
    __builtin_amdgcn_s_setprio(0);                                           \
    __builtin_amdgcn_s_barrier();                                            \
  }

#pragma unroll 1
  for (int tt = 0; tt < 2; ++tt) {
    const int jt = tt ? p : (7 - p);
    const int jBase = jt * 256;
    const int NT = (jt + 1) * 4;  // K-tiles of 64; even (4..32)

    const __hip_bfloat16* bGp0 = Bt + (size_t)(jBase + srow) * M_PTS + scolE;
    const __hip_bfloat16* bGp1 = bGp0 + (size_t)128 * M_PTS;

    f32x4 acc[8][4] = {};
    bf16x8 bF[4][2];

    // ---- prologue: tile0 complete + tile1's B; allow B(1) in flight ----
    STG_A0(0, 0); STG_A1(0, 0); STG_B0(0, 0); STG_B1(0, 0);
    STG_B0(1, 1); STG_B1(1, 1);
    VM4;
    __builtin_amdgcn_s_barrier();

    for (int t = 0; t < NT; t += 2) {
      const bool s2 = (t + 2) < NT, s3 = (t + 3) < NT;
      // P1..P4: tile t from buf0
      PHASE(0, 0, true,  VMNONE, { STG_A0(1, t + 1); });
      PHASE(1, 0, false, VMNONE, { STG_A1(1, t + 1); if (s2) STG_B0(0, t + 2); });
      PHASE(2, 0, false, VMNONE, { if (s2) STG_B1(0, t + 2); });
      if (s2) { PHASE(3, 0, false, VM4, {}); }
      else    { PHASE(3, 0, false, VM0, {}); }
      // P5..P8: tile t+1 from buf1
      PHASE(0, 65536, true,  VMNONE, { if (s2) STG_A0(0, t + 2); });
      PHASE(1, 65536, false, VMNONE, { if (s2) STG_A1(0, t + 2); if (s3) STG_B0(1, t + 3); });
      PHASE(2, 65536, false, VMNONE, { if (s3) STG_B1(1, t + 3); });
      PHASE(3, 65536, false, VM4, {});
    }

    // ---- epilogue: C/D layout col = lane&15, row = q*4 + v [m89] ----
    const int crow = iBase + wm * 128 + q * 4;
    const int ccol = jBase + wn * 64 + r;
#pragma unroll
    for (int m = 0; m < 8; ++m)
#pragma unroll
      for (int nn = 0; nn < 4; ++nn)
#pragma unroll
        for (int v = 0; v < 4; ++v)
          Cmat[(size_t)(crow + m * 16 + v) * M_PTS + (ccol + nn * 16)] =
              acc[m][nn][v];
  }
}

extern "C" void kernel_launch(void* const* d_in, const int* in_sizes, int n_in,
                              void* d_out, int out_size, void* d_ws,
                              size_t ws_size, hipStream_t stream) {
  const float* x    = (const float*)d_in[0];
  const float* z    = (const float*)d_in[1];
  const float* chol = (const float*)d_in[2];
  float* out = (float*)d_out;

  __hip_bfloat16* Kbf = (__hip_bfloat16*)d_ws;                        // 64 MB
  __hip_bfloat16* Bt  = (__hip_bfloat16*)((char*)d_ws +
                        (size_t)N_PTS * M_PTS * sizeof(__hip_bfloat16)); // 8 MB

  laplace_k<<<dim3(N_PTS / 16), 256, 0, stream>>>(x, z, Kbf);
  transpose_cast<<<dim3(M_PTS / 32, M_PTS / 32), dim3(32, 8), 0, stream>>>(
      chol, Bt);
  gemm_bf16_8ph<<<dim3(256), 512, 0, stream>>>(Kbf, Bt, out);
}